// Round 1
// baseline (1267.950 us; speedup 1.0000x reference)
//
#include <hip/hip_runtime.h>

// SparseMCFModel: the GNN (encoder + 2 GAT layers + gate + decoder) provably
// does not affect the outputs. fw = segment_softmax(pred[src], seg=src) is a
// softmax over per-segment-CONSTANT values => fw_e = 1/out_degree(src_e)
// exactly in f32. The flow iteration collapses from edge-space to a node-space
// recurrence p_{k+1} = relu(A p_k - d0) with p_0 = 1, where
// A[n,s] = sum_{e:dst=n,src=s} fw_e. flow = fw * p_10[src]; cost = sum flow^2.

static constexpr int BLK = 256;

__global__ void count_deg_kernel(const int* __restrict__ src, int* __restrict__ deg, int E) {
    int e = blockIdx.x * blockDim.x + threadIdx.x;
    if (e < E) atomicAdd(&deg[src[e]], 1);
}

__global__ void init_kernel(float* __restrict__ p, float* __restrict__ q,
                            float* __restrict__ cost, int N) {
    int n = blockIdx.x * blockDim.x + threadIdx.x;
    if (n < N) { p[n] = 1.0f; q[n] = 0.0f; }
    if (blockIdx.x == 0 && threadIdx.x == 0) cost[0] = 0.0f;
}

__global__ void fw_kernel(const int* __restrict__ src, const int* __restrict__ deg,
                          float* __restrict__ fw_out, int E) {
    int e = blockIdx.x * blockDim.x + threadIdx.x;
    if (e < E) fw_out[e] = 1.0f / ((float)deg[src[e]] + 1e-9f);
}

__global__ void spmv_kernel(const int* __restrict__ src, const int* __restrict__ dst,
                            const float* __restrict__ fw, const float* __restrict__ p,
                            float* __restrict__ q, int E) {
    int e = blockIdx.x * blockDim.x + threadIdx.x;
    if (e < E) atomicAdd(&q[dst[e]], fw[e] * p[src[e]]);
}

__global__ void update_kernel(const float* __restrict__ d0, float* __restrict__ p,
                              float* __restrict__ q, int N) {
    int n = blockIdx.x * blockDim.x + threadIdx.x;
    if (n < N) {
        float v = q[n] - d0[n];
        p[n] = v > 0.0f ? v : 0.0f;
        q[n] = 0.0f;  // pre-zero for next iteration's scatter
    }
}

__global__ void final_kernel(const int* __restrict__ src, const float* __restrict__ fw,
                             const float* __restrict__ p, float* __restrict__ flow,
                             float* __restrict__ cost, int E) {
    int e = blockIdx.x * blockDim.x + threadIdx.x;
    float f2 = 0.0f;
    if (e < E) {
        float f = fw[e] * p[src[e]];
        flow[e] = f;
        f2 = f * f;
    }
    // wave64 reduction, then one atomic per wave
    #pragma unroll
    for (int off = 32; off > 0; off >>= 1) f2 += __shfl_down(f2, off, 64);
    if ((threadIdx.x & 63) == 0) atomicAdd(cost, f2);
}

extern "C" void kernel_launch(void* const* d_in, const int* in_sizes, int n_in,
                              void* d_out, int out_size, void* d_ws, size_t ws_size,
                              hipStream_t stream) {
    const float* demands  = (const float*)d_in[0];  // (N,1)
    const int*   edge_src = (const int*)d_in[2];    // (E,)
    const int*   edge_dst = (const int*)d_in[3];    // (E,)
    const int N = in_sizes[0];
    const int E = in_sizes[2];

    float* out  = (float*)d_out;
    float* cost = out;             // [0]
    float* flow = out + 1;         // [1 .. E]
    float* fw   = out + 1 + E;     // [1+E .. 2E]

    char*  ws  = (char*)d_ws;
    int*   deg = (int*)ws;                           // N ints
    float* p   = (float*)(ws + (size_t)N * 4);       // N floats
    float* q   = (float*)(ws + (size_t)N * 8);       // N floats

    const int gridE = (E + BLK - 1) / BLK;
    const int gridN = (N + BLK - 1) / BLK;

    hipMemsetAsync(deg, 0, (size_t)N * 4, stream);
    count_deg_kernel<<<gridE, BLK, 0, stream>>>(edge_src, deg, E);
    init_kernel<<<gridN, BLK, 0, stream>>>(p, q, cost, N);
    fw_kernel<<<gridE, BLK, 0, stream>>>(edge_src, deg, fw, E);

    for (int it = 0; it < 10; ++it) {
        spmv_kernel<<<gridE, BLK, 0, stream>>>(edge_src, edge_dst, fw, p, q, E);
        update_kernel<<<gridN, BLK, 0, stream>>>(demands, p, q, N);
    }

    final_kernel<<<gridE, BLK, 0, stream>>>(edge_src, fw, p, flow, cost, E);
}

// Round 2
// 427.856 us; speedup vs baseline: 2.9635x; 2.9635x over previous
//
#include <hip/hip_runtime.h>

// SparseMCFModel: the GNN is dead code. fw_e = 1/(outdeg(src_e)+1e-9) exactly
// (softmax over per-segment-constant scores). Flow loop collapses to node
// space: r_0[s] = invdeg[s]; r_{k+1}[n] = relu(sum_{e:dst=n} r_k[src_e] - d0[n])
// * invdeg[n]; flow[e] = r_10[src[e]]; cost = sum flow^2.
//
// Round 1 -> 2: (a) single-address atomicAdd(cost) was 321us of serialization
// -> per-block partials + second reduce kernel; (b) 10x scatter-atomic SpMV
// (~20 G atomics/s bound) -> CSR-by-dst built once on device, gather-based
// atomic-free inner loop; (c) fw stream removed from inner loop via r = p*invdeg.

static constexpr int BLK = 256;
static constexpr int SCAN_BLK = 1024;

__global__ void hist_kernel(const int* __restrict__ src, const int* __restrict__ dst,
                            int* __restrict__ outdeg, int* __restrict__ indeg, int E) {
    int e = blockIdx.x * blockDim.x + threadIdx.x;
    if (e < E) {
        atomicAdd(&outdeg[src[e]], 1);
        atomicAdd(&indeg[dst[e]], 1);
    }
}

__global__ void invdeg_kernel(const int* __restrict__ outdeg, float* __restrict__ invdeg,
                              float* __restrict__ r0, int N) {
    int n = blockIdx.x * blockDim.x + threadIdx.x;
    if (n < N) {
        float v = 1.0f / ((float)outdeg[n] + 1e-9f);
        invdeg[n] = v;
        r0[n] = v;  // r_0 = p_0 * invdeg = 1 * invdeg
    }
}

__global__ void fw_edge_kernel(const int* __restrict__ src, const float* __restrict__ invdeg,
                               float* __restrict__ fw, int E) {
    int e = blockIdx.x * blockDim.x + threadIdx.x;
    if (e < E) fw[e] = invdeg[src[e]];
}

// exclusive scan of indeg -> row_ptr (3 kernels: block scan, partial scan, add)
__global__ void scan_block_kernel(const int* __restrict__ indeg, int* __restrict__ row_ptr,
                                  int* __restrict__ blocksum, int N) {
    __shared__ int lds[SCAN_BLK];
    int t = threadIdx.x;
    int i = blockIdx.x * SCAN_BLK + t;
    int v = (i < N) ? indeg[i] : 0;
    lds[t] = v;
    __syncthreads();
    for (int off = 1; off < SCAN_BLK; off <<= 1) {
        int tmp = (t >= off) ? lds[t - off] : 0;
        __syncthreads();
        lds[t] += tmp;
        __syncthreads();
    }
    if (i < N) row_ptr[i] = lds[t] - v;  // exclusive within block
    if (t == SCAN_BLK - 1) blocksum[blockIdx.x] = lds[t];
}

__global__ void scan_partials_kernel(const int* __restrict__ blocksum,
                                     int* __restrict__ blockoff, int nb) {
    if (blockIdx.x == 0 && threadIdx.x == 0) {
        int acc = 0;
        for (int b = 0; b < nb; ++b) { int t = blocksum[b]; blockoff[b] = acc; acc += t; }
    }
}

__global__ void scan_add_kernel(int* __restrict__ row_ptr, int* __restrict__ cursor,
                                const int* __restrict__ blockoff, int N, int E) {
    int i = blockIdx.x * blockDim.x + threadIdx.x;
    if (i < N) {
        int rp = row_ptr[i] + blockoff[i >> 10];
        row_ptr[i] = rp;
        cursor[i] = rp;
    }
    if (i == 0) row_ptr[N] = E;
}

__global__ void scatter_kernel(const int* __restrict__ src, const int* __restrict__ dst,
                               int* __restrict__ cursor, int* __restrict__ csr_src, int E) {
    int e = blockIdx.x * blockDim.x + threadIdx.x;
    if (e < E) {
        int pos = atomicAdd(&cursor[dst[e]], 1);
        csr_src[pos] = src[e];
    }
}

// one thread per node: q[n] = sum r_in[csr_src[j]]; r_out[n] = relu(q - d0) * invdeg
__global__ void spmv_csr_kernel(const int* __restrict__ row_ptr, const int* __restrict__ csr_src,
                                const float* __restrict__ r_in, const float* __restrict__ d0,
                                const float* __restrict__ invdeg, float* __restrict__ r_out, int N) {
    int n = blockIdx.x * blockDim.x + threadIdx.x;
    if (n >= N) return;
    int beg = row_ptr[n], end = row_ptr[n + 1];
    float acc = 0.0f;
    for (int j = beg; j < end; ++j) acc += r_in[csr_src[j]];
    float p = acc - d0[n];
    p = p > 0.0f ? p : 0.0f;
    r_out[n] = p * invdeg[n];
}

__global__ void final_kernel(const int* __restrict__ src, const float* __restrict__ r_fin,
                             float* __restrict__ flow, float* __restrict__ partials, int E) {
    int e = blockIdx.x * blockDim.x + threadIdx.x;
    float f2 = 0.0f;
    if (e < E) {
        float f = r_fin[src[e]];
        flow[e] = f;
        f2 = f * f;
    }
    #pragma unroll
    for (int off = 32; off > 0; off >>= 1) f2 += __shfl_down(f2, off, 64);
    __shared__ float wsum[BLK / 64];
    int lane = threadIdx.x & 63, w = threadIdx.x >> 6;
    if (lane == 0) wsum[w] = f2;
    __syncthreads();
    if (threadIdx.x == 0) {
        float s = 0.0f;
        #pragma unroll
        for (int k = 0; k < BLK / 64; ++k) s += wsum[k];
        partials[blockIdx.x] = s;  // no atomic: avoids same-address serialization
    }
}

__global__ void reduce_cost_kernel(const float* __restrict__ partials, float* __restrict__ cost, int n) {
    float s = 0.0f;
    for (int i = threadIdx.x; i < n; i += blockDim.x) s += partials[i];
    #pragma unroll
    for (int off = 32; off > 0; off >>= 1) s += __shfl_down(s, off, 64);
    __shared__ float wsum[16];
    int lane = threadIdx.x & 63, w = threadIdx.x >> 6;
    if (lane == 0) wsum[w] = s;
    __syncthreads();
    if (threadIdx.x == 0) {
        float t = 0.0f;
        for (int k = 0; k < (int)(blockDim.x / 64); ++k) t += wsum[k];
        cost[0] = t;
    }
}

extern "C" void kernel_launch(void* const* d_in, const int* in_sizes, int n_in,
                              void* d_out, int out_size, void* d_ws, size_t ws_size,
                              hipStream_t stream) {
    const float* demands  = (const float*)d_in[0];  // (N,1) contiguous N floats
    const int*   edge_src = (const int*)d_in[2];
    const int*   edge_dst = (const int*)d_in[3];
    const int N = in_sizes[0];
    const int E = in_sizes[2];

    float* out  = (float*)d_out;
    float* cost = out;
    float* flow = out + 1;
    float* fw   = out + 1 + E;

    const int gridE = (E + BLK - 1) / BLK;
    const int gridN = (N + BLK - 1) / BLK;
    const int nb    = (N + SCAN_BLK - 1) / SCAN_BLK;

    auto align16 = [](size_t x) { return (x + 15) & ~size_t(15); };
    char* ws = (char*)d_ws;
    size_t o = 0;
    int*   outdeg  = (int*)(ws + o); o += align16((size_t)N * 4);
    int*   indeg   = (int*)(ws + o); o += align16((size_t)N * 4);   // contiguous w/ outdeg
    int*   row_ptr = (int*)(ws + o); o += align16((size_t)(N + 1) * 4);
    int*   cursor  = (int*)(ws + o); o += align16((size_t)N * 4);
    int*   csr_src = (int*)(ws + o); o += align16((size_t)E * 4);
    float* invdeg  = (float*)(ws + o); o += align16((size_t)N * 4);
    float* r0      = (float*)(ws + o); o += align16((size_t)N * 4);
    float* r1      = (float*)(ws + o); o += align16((size_t)N * 4);
    int*   blocksum= (int*)(ws + o); o += align16((size_t)nb * 4);
    int*   blockoff= (int*)(ws + o); o += align16((size_t)nb * 4);
    float* partials= (float*)(ws + o); o += align16((size_t)gridE * 4);

    // zero both histograms in one memset (they are adjacent)
    hipMemsetAsync(outdeg, 0, align16((size_t)N * 4) + (size_t)N * 4, stream);

    hist_kernel<<<gridE, BLK, 0, stream>>>(edge_src, edge_dst, outdeg, indeg, E);
    invdeg_kernel<<<gridN, BLK, 0, stream>>>(outdeg, invdeg, r0, N);
    fw_edge_kernel<<<gridE, BLK, 0, stream>>>(edge_src, invdeg, fw, E);

    scan_block_kernel<<<nb, SCAN_BLK, 0, stream>>>(indeg, row_ptr, blocksum, N);
    scan_partials_kernel<<<1, 64, 0, stream>>>(blocksum, blockoff, nb);
    scan_add_kernel<<<gridN, BLK, 0, stream>>>(row_ptr, cursor, blockoff, N, E);
    scatter_kernel<<<gridE, BLK, 0, stream>>>(edge_src, edge_dst, cursor, csr_src, E);

    float* r_cur = r0;
    float* r_nxt = r1;
    for (int it = 0; it < 10; ++it) {
        spmv_csr_kernel<<<gridN, BLK, 0, stream>>>(row_ptr, csr_src, r_cur, demands, invdeg, r_nxt, N);
        float* t = r_cur; r_cur = r_nxt; r_nxt = t;
    }

    final_kernel<<<gridE, BLK, 0, stream>>>(edge_src, r_cur, flow, partials, E);
    reduce_cost_kernel<<<1, 1024, 0, stream>>>(partials, cost, gridE);
}

// Round 3
// 283.805 us; speedup vs baseline: 4.4677x; 1.5076x over previous
//
#include <hip/hip_runtime.h>

// SparseMCFModel: the GNN is dead code. fw_e = 1/(outdeg(src_e)+1e-9) exactly
// (softmax over per-segment-constant scores). Flow loop collapses to node
// space: r_0 = invdeg; r_{k+1}[n] = relu(sum_{e:dst=n} r_k[src_e] - d0[n]) *
// invdeg[n]; flow[e] = r_10[src[e]]; cost = sum flow^2.
//
// R1->R2: removed single-address cost atomic, CSR gather spmv.   1268 -> 428 us
// R2->R3: global atomics write through to memory side (32 B each, ~26 G/s):
//   hist (3.2M atomics, 100 MB WRITE) + scatter (1.6M atomics + scattered
//   writes) were ~250 us. Replace per-node CSR with ATOMIC-FREE bucket
//   partition by dst>>7 (782 buckets x 128 nodes): per-block LDS histograms,
//   2-level scan of [bin][block] counts, rank-scatter via LDS cursors.
//   Inner spmv: one block per bucket, LDS float accumulation, packed uint32
//   edges (src | ldst<<17) = 6.4 MB/iter. Remaining global atomics: only the
//   outdeg histogram (fused into the partition-hist pass). fw fused into
//   scatter (reads src anyway).

static constexpr int BLK      = 256;
static constexpr int SCAN_BLK = 1024;
static constexpr int CHUNK    = 16384;  // edges per partition block
static constexpr int LB       = 7;      // log2(bucket nodes)
static constexpr int BN       = 128;    // nodes per bucket

// Pass 1: per-block LDS histogram over buckets (dst>>LB) + global outdeg atomics.
__global__ void hist_kernel(const int* __restrict__ src, const int* __restrict__ dst,
                            int* __restrict__ outdeg, int* __restrict__ counts,
                            int E, int B, int nb) {
    extern __shared__ int lh[];
    for (int i = threadIdx.x; i < B; i += blockDim.x) lh[i] = 0;
    __syncthreads();
    int base = blockIdx.x * CHUNK;
    int end  = base + CHUNK < E ? base + CHUNK : E;
    for (int e = base + threadIdx.x; e < end; e += blockDim.x) {
        atomicAdd(&outdeg[src[e]], 1);       // only remaining global atomic
        atomicAdd(&lh[dst[e] >> LB], 1);     // LDS: no write-through
    }
    __syncthreads();
    for (int i = threadIdx.x; i < B; i += blockDim.x)
        counts[i * nb + blockIdx.x] = lh[i]; // bin-major for grouping scan
}

__global__ void invdeg_kernel(const int* __restrict__ outdeg, float* __restrict__ invdeg,
                              float* __restrict__ r0, int N) {
    int n = blockIdx.x * blockDim.x + threadIdx.x;
    if (n < N) {
        float v = 1.0f / ((float)outdeg[n] + 1e-9f);
        invdeg[n] = v;
        r0[n] = v;  // r_0 = 1 * invdeg
    }
}

// exclusive scan of counts[M] -> coff[M]
__global__ void scan_block_kernel(const int* __restrict__ in, int* __restrict__ out,
                                  int* __restrict__ blocksum, int M) {
    __shared__ int lds[SCAN_BLK];
    int t = threadIdx.x;
    int i = blockIdx.x * SCAN_BLK + t;
    int v = (i < M) ? in[i] : 0;
    lds[t] = v;
    __syncthreads();
    for (int off = 1; off < SCAN_BLK; off <<= 1) {
        int tmp = (t >= off) ? lds[t - off] : 0;
        __syncthreads();
        lds[t] += tmp;
        __syncthreads();
    }
    if (i < M) out[i] = lds[t] - v;
    if (t == SCAN_BLK - 1) blocksum[blockIdx.x] = lds[t];
}

__global__ void scan_partials_kernel(const int* __restrict__ blocksum,
                                     int* __restrict__ blockoff, int nbs) {
    if (blockIdx.x == 0 && threadIdx.x == 0) {
        int acc = 0;
        for (int b = 0; b < nbs; ++b) { int t = blocksum[b]; blockoff[b] = acc; acc += t; }
    }
}

__global__ void scan_add_kernel(int* __restrict__ coff, const int* __restrict__ blockoff, int M) {
    int i = blockIdx.x * blockDim.x + threadIdx.x;
    if (i < M) coff[i] += blockoff[i >> 10];
}

// Pass 2: rank-scatter into bucket-grouped packed edges; fw fused (reads src anyway).
__global__ void scatter_kernel(const int* __restrict__ src, const int* __restrict__ dst,
                               const float* __restrict__ invdeg, const int* __restrict__ coff,
                               unsigned* __restrict__ packed, float* __restrict__ fw,
                               int E, int B, int nb) {
    extern __shared__ int loff[];
    for (int i = threadIdx.x; i < B; i += blockDim.x)
        loff[i] = coff[i * nb + blockIdx.x];
    __syncthreads();
    int base = blockIdx.x * CHUNK;
    int end  = base + CHUNK < E ? base + CHUNK : E;
    for (int e = base + threadIdx.x; e < end; e += blockDim.x) {
        int s = src[e], d = dst[e];
        int pos = atomicAdd(&loff[d >> LB], 1);  // LDS cursor: block owns disjoint ranges
        packed[pos] = (unsigned)s | ((unsigned)(d & (BN - 1)) << 17);
        fw[e] = invdeg[s];
    }
}

// One block per bucket: LDS accumulate, fused relu/scale flush.
__global__ void spmv_bucket_kernel(const unsigned* __restrict__ packed, const int* __restrict__ coff,
                                   const float* __restrict__ r_in, const float* __restrict__ d0,
                                   const float* __restrict__ invdeg, float* __restrict__ r_out,
                                   int N, int E, int nb, int B) {
    __shared__ float q[BN];
    int b = blockIdx.x;
    if (threadIdx.x < BN) q[threadIdx.x] = 0.0f;
    __syncthreads();
    int beg = coff[b * nb];
    int end = (b + 1 < B) ? coff[(b + 1) * nb] : E;
    for (int e = beg + threadIdx.x; e < end; e += blockDim.x) {
        unsigned v = packed[e];
        atomicAdd(&q[v >> 17], r_in[v & 0x1FFFFu]);  // LDS float atomic
    }
    __syncthreads();
    int g = (b << LB) + threadIdx.x;
    if (threadIdx.x < BN && g < N) {
        float p = q[threadIdx.x] - d0[g];
        p = p > 0.0f ? p : 0.0f;
        r_out[g] = p * invdeg[g];
    }
}

__global__ void final_kernel(const int* __restrict__ src, const float* __restrict__ r_fin,
                             float* __restrict__ flow, float* __restrict__ partials, int E) {
    int e = blockIdx.x * blockDim.x + threadIdx.x;
    float f2 = 0.0f;
    if (e < E) {
        float f = r_fin[src[e]];
        flow[e] = f;
        f2 = f * f;
    }
    #pragma unroll
    for (int off = 32; off > 0; off >>= 1) f2 += __shfl_down(f2, off, 64);
    __shared__ float wsum[BLK / 64];
    int lane = threadIdx.x & 63, w = threadIdx.x >> 6;
    if (lane == 0) wsum[w] = f2;
    __syncthreads();
    if (threadIdx.x == 0) {
        float s = 0.0f;
        #pragma unroll
        for (int k = 0; k < BLK / 64; ++k) s += wsum[k];
        partials[blockIdx.x] = s;
    }
}

__global__ void reduce_cost_kernel(const float* __restrict__ partials, float* __restrict__ cost, int n) {
    float s = 0.0f;
    for (int i = threadIdx.x; i < n; i += blockDim.x) s += partials[i];
    #pragma unroll
    for (int off = 32; off > 0; off >>= 1) s += __shfl_down(s, off, 64);
    __shared__ float wsum[16];
    int lane = threadIdx.x & 63, w = threadIdx.x >> 6;
    if (lane == 0) wsum[w] = s;
    __syncthreads();
    if (threadIdx.x == 0) {
        float t = 0.0f;
        for (int k = 0; k < (int)(blockDim.x / 64); ++k) t += wsum[k];
        cost[0] = t;
    }
}

extern "C" void kernel_launch(void* const* d_in, const int* in_sizes, int n_in,
                              void* d_out, int out_size, void* d_ws, size_t ws_size,
                              hipStream_t stream) {
    const float* demands  = (const float*)d_in[0];
    const int*   edge_src = (const int*)d_in[2];
    const int*   edge_dst = (const int*)d_in[3];
    const int N = in_sizes[0];
    const int E = in_sizes[2];

    float* out  = (float*)d_out;
    float* cost = out;
    float* flow = out + 1;
    float* fw   = out + 1 + E;

    const int B     = (N + BN - 1) >> LB;            // buckets
    const int nb    = (E + CHUNK - 1) / CHUNK;       // partition blocks
    const int M     = B * nb;                        // counts matrix
    const int nbs   = (M + SCAN_BLK - 1) / SCAN_BLK; // scan blocks
    const int gridE = (E + BLK - 1) / BLK;
    const int gridN = (N + BLK - 1) / BLK;

    auto align16 = [](size_t x) { return (x + 15) & ~size_t(15); };
    char* ws = (char*)d_ws;
    size_t o = 0;
    int*      outdeg   = (int*)(ws + o);      o += align16((size_t)N * 4);
    float*    invdeg   = (float*)(ws + o);    o += align16((size_t)N * 4);
    float*    r0       = (float*)(ws + o);    o += align16((size_t)N * 4);
    float*    r1       = (float*)(ws + o);    o += align16((size_t)N * 4);
    int*      counts   = (int*)(ws + o);      o += align16((size_t)M * 4);
    int*      coff     = (int*)(ws + o);      o += align16((size_t)M * 4);
    int*      blocksum = (int*)(ws + o);      o += align16((size_t)nbs * 4);
    int*      blockoff = (int*)(ws + o);      o += align16((size_t)nbs * 4);
    unsigned* packed   = (unsigned*)(ws + o); o += align16((size_t)E * 4);
    float*    partials = (float*)(ws + o);    o += align16((size_t)gridE * 4);

    hipMemsetAsync(outdeg, 0, (size_t)N * 4, stream);

    hist_kernel<<<nb, BLK, (size_t)B * 4, stream>>>(edge_src, edge_dst, outdeg, counts, E, B, nb);
    invdeg_kernel<<<gridN, BLK, 0, stream>>>(outdeg, invdeg, r0, N);

    scan_block_kernel<<<nbs, SCAN_BLK, 0, stream>>>(counts, coff, blocksum, M);
    scan_partials_kernel<<<1, 64, 0, stream>>>(blocksum, blockoff, nbs);
    scan_add_kernel<<<(M + BLK - 1) / BLK, BLK, 0, stream>>>(coff, blockoff, M);

    scatter_kernel<<<nb, BLK, (size_t)B * 4, stream>>>(edge_src, edge_dst, invdeg, coff,
                                                       packed, fw, E, B, nb);

    float* r_cur = r0;
    float* r_nxt = r1;
    for (int it = 0; it < 10; ++it) {
        spmv_bucket_kernel<<<B, BLK, 0, stream>>>(packed, coff, r_cur, demands, invdeg, r_nxt, N, E, nb, B);
        float* t = r_cur; r_cur = r_nxt; r_nxt = t;
    }

    final_kernel<<<gridE, BLK, 0, stream>>>(edge_src, r_cur, flow, partials, E);
    reduce_cost_kernel<<<1, 1024, 0, stream>>>(partials, cost, gridE);
}

// Round 4
// 219.018 us; speedup vs baseline: 5.7893x; 1.2958x over previous
//
#include <hip/hip_runtime.h>

// SparseMCFModel: the GNN is dead code. fw_e = 1/(outdeg(src_e)+1e-9) exactly
// (softmax over per-segment-constant scores). Flow loop collapses to node
// space: r_0 = invdeg; r_{k+1}[n] = relu(sum_{e:dst=n} r_k[src_e] - d0[n]) *
// invdeg[n]; flow[e] = r_10[src[e]]; cost = sum flow^2.
//
// R1->R2: no single-address cost atomic; CSR gather spmv.       1268 -> 428 us
// R2->R3: bucket partition (atomic-free except outdeg hist).     428 -> 284 us
// R3->R4: outdeg global atomics (1.6M x 32B write-through, 52 MB, 93 us @ 3%
//   occupancy) eliminated: hist builds BOTH src/dst coarse LDS histograms,
//   ONE concatenated scan, byte-scatter of src&127 by src-bucket, per-bucket
//   LDS count -> invdeg. ZERO global atomics anywhere. CHUNK 16384->4096
//   (98->391 blocks). Parallel scan_partials. Per-wave replicated spmv
//   accumulators. int4-vectorized final. psrc aliases packed (ws ~10 MB).

static constexpr int BLK      = 256;
static constexpr int SCAN_BLK = 1024;
static constexpr int CHUNK    = 4096;   // edges per partition block
static constexpr int LB       = 7;      // log2(nodes per bucket)
static constexpr int BN       = 128;    // nodes per bucket

// Pass 1: per-block LDS histograms over dst-buckets AND src-buckets.
__global__ void hist_kernel(const int* __restrict__ src, const int* __restrict__ dst,
                            int* __restrict__ counts, int E, int B, int nb, int M) {
    extern __shared__ int lh[];          // [0,B): dst bins, [B,2B): src bins
    int* lhd = lh;
    int* lhs = lh + B;
    for (int i = threadIdx.x; i < 2 * B; i += blockDim.x) lh[i] = 0;
    __syncthreads();
    int base = blockIdx.x * CHUNK;
    int end  = base + CHUNK < E ? base + CHUNK : E;
    for (int e = base + threadIdx.x; e < end; e += blockDim.x) {
        atomicAdd(&lhd[dst[e] >> LB], 1);   // LDS only — no write-through
        atomicAdd(&lhs[src[e] >> LB], 1);
    }
    __syncthreads();
    for (int i = threadIdx.x; i < B; i += blockDim.x) {
        counts[i * nb + blockIdx.x]     = lhd[i];   // bin-major
        counts[M + i * nb + blockIdx.x] = lhs[i];
    }
}

// exclusive scan of counts[M2] in place (3 kernels)
__global__ void scan_block_kernel(int* __restrict__ data, int* __restrict__ blocksum, int M2) {
    __shared__ int lds[SCAN_BLK];
    int t = threadIdx.x;
    int i = blockIdx.x * SCAN_BLK + t;
    int v = (i < M2) ? data[i] : 0;
    lds[t] = v;
    __syncthreads();
    for (int off = 1; off < SCAN_BLK; off <<= 1) {
        int tmp = (t >= off) ? lds[t - off] : 0;
        __syncthreads();
        lds[t] += tmp;
        __syncthreads();
    }
    if (i < M2) data[i] = lds[t] - v;
    if (t == SCAN_BLK - 1) blocksum[blockIdx.x] = lds[t];
}

// single-block parallel scan of blocksum -> blockoff (exclusive)
__global__ void scan_partials_kernel(const int* __restrict__ bsum, int* __restrict__ boff, int n) {
    __shared__ int lds[SCAN_BLK];
    __shared__ int carry_s;
    if (threadIdx.x == 0) carry_s = 0;
    __syncthreads();
    for (int base = 0; base < n; base += SCAN_BLK) {
        int i = base + threadIdx.x;
        int v = (i < n) ? bsum[i] : 0;
        lds[threadIdx.x] = v;
        __syncthreads();
        for (int off = 1; off < SCAN_BLK; off <<= 1) {
            int tmp = (threadIdx.x >= off) ? lds[threadIdx.x - off] : 0;
            __syncthreads();
            lds[threadIdx.x] += tmp;
            __syncthreads();
        }
        int incl = lds[threadIdx.x];
        int c = carry_s;
        if (i < n) boff[i] = c + incl - v;
        __syncthreads();
        if (threadIdx.x == SCAN_BLK - 1) carry_s = c + incl;
        __syncthreads();
    }
}

__global__ void scan_add_kernel(int* __restrict__ data, const int* __restrict__ boff, int M2) {
    int i = blockIdx.x * blockDim.x + threadIdx.x;
    if (i < M2) data[i] += boff[i >> 10];
}

// Pass 2a: byte-scatter src&127 grouped by src-bucket (for atomic-free outdeg).
__global__ void scatter_src_kernel(const int* __restrict__ src, const int* __restrict__ coff,
                                   unsigned char* __restrict__ psrc, int E, int B, int nb, int M) {
    extern __shared__ int loff[];
    for (int i = threadIdx.x; i < B; i += blockDim.x)
        loff[i] = coff[M + i * nb + blockIdx.x] - E;   // src half starts at E
    __syncthreads();
    int base = blockIdx.x * CHUNK;
    int end  = base + CHUNK < E ? base + CHUNK : E;
    for (int e = base + threadIdx.x; e < end; e += blockDim.x) {
        int s = src[e];
        int pos = atomicAdd(&loff[s >> LB], 1);        // LDS cursor
        psrc[pos] = (unsigned char)(s & (BN - 1));
    }
}

// Pass 2b: per src-bucket fine count -> invdeg, r0. No global atomics.
__global__ void count_src_kernel(const unsigned char* __restrict__ psrc, const int* __restrict__ coff,
                                 float* __restrict__ invdeg, float* __restrict__ r0,
                                 int N, int E, int B, int nb, int M) {
    __shared__ int cnt[BN];
    if (threadIdx.x < BN) cnt[threadIdx.x] = 0;
    __syncthreads();
    int b = blockIdx.x;
    int beg = coff[M + b * nb] - E;
    int end = (b + 1 < B) ? coff[M + (b + 1) * nb] - E : E;
    for (int e = beg + threadIdx.x; e < end; e += blockDim.x)
        atomicAdd(&cnt[psrc[e]], 1);
    __syncthreads();
    int g = (b << LB) + threadIdx.x;
    if (threadIdx.x < BN && g < N) {
        float v = 1.0f / ((float)cnt[threadIdx.x] + 1e-9f);
        invdeg[g] = v;
        r0[g] = v;   // r_0 = 1 * invdeg
    }
}

// Pass 3: scatter packed edges (src | ldst<<17) grouped by dst-bucket; fw fused.
__global__ void scatter_dst_kernel(const int* __restrict__ src, const int* __restrict__ dst,
                                   const float* __restrict__ invdeg, const int* __restrict__ coff,
                                   unsigned* __restrict__ packed, float* __restrict__ fw,
                                   int E, int B, int nb) {
    extern __shared__ int loff[];
    for (int i = threadIdx.x; i < B; i += blockDim.x)
        loff[i] = coff[i * nb + blockIdx.x];
    __syncthreads();
    int base = blockIdx.x * CHUNK;
    int end  = base + CHUNK < E ? base + CHUNK : E;
    for (int e = base + threadIdx.x; e < end; e += blockDim.x) {
        int s = src[e], d = dst[e];
        int pos = atomicAdd(&loff[d >> LB], 1);
        packed[pos] = (unsigned)s | ((unsigned)(d & (BN - 1)) << 17);
        fw[e] = invdeg[s];
    }
}

// Inner loop: one block per dst-bucket, per-wave replicated LDS accumulators.
__global__ void spmv_bucket_kernel(const unsigned* __restrict__ packed, const int* __restrict__ coff,
                                   const float* __restrict__ r_in, const float* __restrict__ d0,
                                   const float* __restrict__ invdeg, float* __restrict__ r_out,
                                   int N, int E, int nb, int B) {
    __shared__ float q[4 * BN];
    for (int i = threadIdx.x; i < 4 * BN; i += blockDim.x) q[i] = 0.0f;
    __syncthreads();
    int b = blockIdx.x;
    int w = threadIdx.x >> 6;
    int beg = coff[b * nb];
    int end = (b + 1 < B) ? coff[(b + 1) * nb] : E;
    for (int e = beg + threadIdx.x; e < end; e += blockDim.x) {
        unsigned v = packed[e];
        atomicAdd(&q[(w << LB) + (v >> 17)], r_in[v & 0x1FFFFu]);  // LDS float atomic
    }
    __syncthreads();
    int g = (b << LB) + threadIdx.x;
    if (threadIdx.x < BN && g < N) {
        float p = q[threadIdx.x] + q[BN + threadIdx.x] + q[2 * BN + threadIdx.x] + q[3 * BN + threadIdx.x] - d0[g];
        p = p > 0.0f ? p : 0.0f;
        r_out[g] = p * invdeg[g];
    }
}

// flow[e] = r10[src[e]]; partial sums of flow^2. int4 loads; scalar stores
// (flow = out+1 is only 4B-aligned).
__global__ void final_kernel(const int* __restrict__ src, const float* __restrict__ r_fin,
                             float* __restrict__ flow, float* __restrict__ partials, int E) {
    int i = blockIdx.x * blockDim.x + threadIdx.x;
    int E4 = E >> 2;
    float f2 = 0.0f;
    if (i < E4) {
        int4 s4 = ((const int4*)src)[i];
        float a = r_fin[s4.x], b = r_fin[s4.y], c = r_fin[s4.z], d = r_fin[s4.w];
        int e = i << 2;
        flow[e] = a; flow[e + 1] = b; flow[e + 2] = c; flow[e + 3] = d;
        f2 = a * a + b * b + c * c + d * d;
    }
    if (blockIdx.x == 0 && threadIdx.x == 0) {   // tail (E % 4)
        for (int e = E4 << 2; e < E; ++e) {
            float f = r_fin[src[e]];
            flow[e] = f;
            f2 += f * f;
        }
    }
    #pragma unroll
    for (int off = 32; off > 0; off >>= 1) f2 += __shfl_down(f2, off, 64);
    __shared__ float wsum[BLK / 64];
    int lane = threadIdx.x & 63, w = threadIdx.x >> 6;
    if (lane == 0) wsum[w] = f2;
    __syncthreads();
    if (threadIdx.x == 0) {
        float s = 0.0f;
        #pragma unroll
        for (int k = 0; k < BLK / 64; ++k) s += wsum[k];
        partials[blockIdx.x] = s;
    }
}

__global__ void reduce_cost_kernel(const float* __restrict__ partials, float* __restrict__ cost, int n) {
    float s = 0.0f;
    for (int i = threadIdx.x; i < n; i += blockDim.x) s += partials[i];
    #pragma unroll
    for (int off = 32; off > 0; off >>= 1) s += __shfl_down(s, off, 64);
    __shared__ float wsum[16];
    int lane = threadIdx.x & 63, w = threadIdx.x >> 6;
    if (lane == 0) wsum[w] = s;
    __syncthreads();
    if (threadIdx.x == 0) {
        float t = 0.0f;
        for (int k = 0; k < (int)(blockDim.x / 64); ++k) t += wsum[k];
        cost[0] = t;
    }
}

extern "C" void kernel_launch(void* const* d_in, const int* in_sizes, int n_in,
                              void* d_out, int out_size, void* d_ws, size_t ws_size,
                              hipStream_t stream) {
    const float* demands  = (const float*)d_in[0];
    const int*   edge_src = (const int*)d_in[2];
    const int*   edge_dst = (const int*)d_in[3];
    const int N = in_sizes[0];
    const int E = in_sizes[2];

    float* out  = (float*)d_out;
    float* cost = out;
    float* flow = out + 1;
    float* fw   = out + 1 + E;

    const int B   = (N + BN - 1) >> LB;              // buckets
    const int nb  = (E + CHUNK - 1) / CHUNK;         // partition blocks
    const int M   = B * nb;                          // per-key counts matrix
    const int M2  = 2 * M;                           // dst + src concatenated
    const int nbs = (M2 + SCAN_BLK - 1) / SCAN_BLK;  // scan blocks
    const int gridF = ((E >> 2) + BLK - 1) / BLK;    // final (vec4)

    auto align16 = [](size_t x) { return (x + 15) & ~size_t(15); };
    char* ws = (char*)d_ws;
    size_t o = 0;
    float*    invdeg   = (float*)(ws + o);    o += align16((size_t)N * 4);
    float*    r0       = (float*)(ws + o);    o += align16((size_t)N * 4);
    float*    r1       = (float*)(ws + o);    o += align16((size_t)N * 4);
    int*      counts   = (int*)(ws + o);      o += align16((size_t)M2 * 4);
    int*      blocksum = (int*)(ws + o);      o += align16((size_t)nbs * 4);
    int*      blockoff = (int*)(ws + o);      o += align16((size_t)nbs * 4);
    unsigned* packed   = (unsigned*)(ws + o); o += align16((size_t)E * 4);
    float*    partials = (float*)(ws + o);    o += align16((size_t)gridF * 4);
    // psrc aliases packed: written/read before packed is produced, dead after.
    unsigned char* psrc = (unsigned char*)packed;

    hist_kernel<<<nb, BLK, (size_t)(2 * B) * 4, stream>>>(edge_src, edge_dst, counts, E, B, nb, M);

    scan_block_kernel<<<nbs, SCAN_BLK, 0, stream>>>(counts, blocksum, M2);
    scan_partials_kernel<<<1, SCAN_BLK, 0, stream>>>(blocksum, blockoff, nbs);
    scan_add_kernel<<<(M2 + BLK - 1) / BLK, BLK, 0, stream>>>(counts, blockoff, M2);

    scatter_src_kernel<<<nb, BLK, (size_t)B * 4, stream>>>(edge_src, counts, psrc, E, B, nb, M);
    count_src_kernel<<<B, BLK, 0, stream>>>(psrc, counts, invdeg, r0, N, E, B, nb, M);

    scatter_dst_kernel<<<nb, BLK, (size_t)B * 4, stream>>>(edge_src, edge_dst, invdeg, counts,
                                                           packed, fw, E, B, nb);

    float* r_cur = r0;
    float* r_nxt = r1;
    for (int it = 0; it < 10; ++it) {
        spmv_bucket_kernel<<<B, BLK, 0, stream>>>(packed, counts, r_cur, demands, invdeg, r_nxt, N, E, nb, B);
        float* t = r_cur; r_cur = r_nxt; r_nxt = t;
    }

    final_kernel<<<gridF, BLK, 0, stream>>>(edge_src, r_cur, flow, partials, E);
    reduce_cost_kernel<<<1, 1024, 0, stream>>>(partials, cost, gridF);
}